// Round 2
// baseline (366.700 us; speedup 1.0000x reference)
//
#include <hip/hip_runtime.h>
#include <stdint.h>

// Problem constants
#define S2048 2048
#define DMODEL 256
#define NH 4
#define DK 64
// tokens total = 8*2048 = 16384

typedef __bf16 bf16x8 __attribute__((ext_vector_type(8)));
typedef float f32x4 __attribute__((ext_vector_type(4)));

#define MFMA16(a, b, c) __builtin_amdgcn_mfma_f32_16x16x32_bf16((a), (b), (c), 0, 0, 0)

__device__ __forceinline__ uint16_t f2bf(float f) {
  uint32_t u = __builtin_bit_cast(uint32_t, f);
  u = (u + 0x7fff + ((u >> 16) & 1)) >> 16;  // RNE; inputs are finite
  return (uint16_t)u;
}

__device__ __forceinline__ void async16(const void* g, void* l) {
  __builtin_amdgcn_global_load_lds(
      (const __attribute__((address_space(1))) unsigned int*)g,
      (__attribute__((address_space(3))) unsigned int*)l, 16, 0, 0);
}

// Stage `rows` x 64 bf16 (128B/row) from global into LDS, 16B chunks,
// chunk-XOR-swizzled so MFMA fragment reads are >=2-way-free on banks.
// rows must be a multiple of 32. 256 threads.
__device__ __forceinline__ void stage64(const char* gbase, int rstride,
                                        char* lds, int tid, int rows) {
  int iters = rows >> 5;
#pragma unroll
  for (int it = 0; it < iters; ++it) {
    int cid = (it << 8) + tid;
    int m = cid >> 3, cp = cid & 7, c = cp ^ (m & 7);
    async16(gbase + (size_t)m * rstride + (c << 4),
            lds + ((size_t)((it << 8) + (tid & ~63)) << 4));
  }
}

// Read one 16B MFMA fragment (A or B^T operand) from a swizzled tile.
// chunk = ks*4 + (lane>>4); row = rowbase + (lane&15)
__device__ __forceinline__ bf16x8 frag_ld(const char* t, int rowbase, int chunk, int l15) {
  int m = rowbase + l15;
  return *(const bf16x8*)(t + (((m << 3) + (chunk ^ (m & 7))) << 4));
}

// ---------------- cast fp32 -> bf16 for query/key/value ----------------
__global__ __launch_bounds__(256) void cast_x(const float* __restrict__ q,
                                              const float* __restrict__ k,
                                              const float* __restrict__ v,
                                              uint16_t* __restrict__ xq,
                                              uint16_t* __restrict__ xk,
                                              uint16_t* __restrict__ xv) {
  const float* src = blockIdx.y == 0 ? q : (blockIdx.y == 1 ? k : v);
  uint16_t* dst = blockIdx.y == 0 ? xq : (blockIdx.y == 1 ? xk : xv);
  size_t i = ((size_t)blockIdx.x * 256 + threadIdx.x) * 8;
  float4 a = *(const float4*)(src + i);
  float4 b = *(const float4*)(src + i + 4);
  union { uint16_t s[8]; uint4 u; } r;
  r.s[0] = f2bf(a.x); r.s[1] = f2bf(a.y); r.s[2] = f2bf(a.z); r.s[3] = f2bf(a.w);
  r.s[4] = f2bf(b.x); r.s[5] = f2bf(b.y); r.s[6] = f2bf(b.z); r.s[7] = f2bf(b.w);
  *(uint4*)(dst + i) = r.u;
}

// ---------------- cast + transpose weights (256x256): Wt[n][k] = W[k][n] ----
__global__ __launch_bounds__(256) void cast_w(const float* __restrict__ Wq,
                                              const float* __restrict__ Wk,
                                              const float* __restrict__ Wv,
                                              const float* __restrict__ Wo,
                                              uint16_t* __restrict__ Wqt,
                                              uint16_t* __restrict__ Wkt,
                                              uint16_t* __restrict__ Wvt,
                                              uint16_t* __restrict__ Wot) {
  const float* W = blockIdx.y == 0 ? Wq : blockIdx.y == 1 ? Wk : blockIdx.y == 2 ? Wv : Wo;
  uint16_t* Wt = blockIdx.y == 0 ? Wqt : blockIdx.y == 1 ? Wkt : blockIdx.y == 2 ? Wvt : Wot;
  __shared__ uint16_t t[64 * 66];  // pitch 66 -> conflict-free column reads
  int tile = blockIdx.x, tr = tile >> 2, tc = tile & 3;
  int tid = threadIdx.x;
#pragma unroll
  for (int i = 0; i < 16; ++i) {
    int e = i * 256 + tid, r = e >> 6, cl = e & 63;
    t[r * 66 + cl] = f2bf(W[(size_t)(tr * 64 + r) * 256 + tc * 64 + cl]);
  }
  __syncthreads();
#pragma unroll
  for (int i = 0; i < 16; ++i) {
    int e = i * 256 + tid, n = e >> 6, kk = e & 63;
    Wt[(size_t)(tc * 64 + n) * 256 + tr * 64 + kk] = t[kk * 66 + n];
  }
}

// ---------------- generic bt-GEMM: C[M,N] = A(MxK) * Bt(NxK)^T (+bias) ------
// tile 128x128, BK=64, 256 threads (2x2 waves of 64x64). grid=(M/128, N/128)
// OUTF32: 0 -> bf16 out, 1 -> fp32 out. BIAS: 0 none, 1 col bias[n], 2 row bias[m]
template <int OUTF32, int BIAS>
__global__ __launch_bounds__(256) void gemm_bt(const uint16_t* __restrict__ A,
                                               const uint16_t* __restrict__ Bt,
                                               const float* __restrict__ bias,
                                               void* __restrict__ Cv, int K, int ldc) {
  __shared__ char lds[32768];
  char* At = lds;
  char* Btl = lds + 16384;
  int tid = threadIdx.x, lane = tid & 63, wid = tid >> 6;
  int l15 = lane & 15, q = lane >> 4;
  int mt = blockIdx.x, nt = blockIdx.y;
  int wm = (wid >> 1) * 64, wn = (wid & 1) * 64;
  f32x4 acc[4][4] = {};
  const char* Ag = (const char*)(A + (size_t)(mt * 128) * K);
  const char* Bg = (const char*)(Bt + (size_t)(nt * 128) * K);
  int nk = K >> 6;
  for (int kt = 0; kt < nk; ++kt) {
    stage64(Ag + kt * 128, K * 2, At, tid, 128);
    stage64(Bg + kt * 128, K * 2, Btl, tid, 128);
    __syncthreads();
#pragma unroll
    for (int ks = 0; ks < 2; ++ks) {
      bf16x8 a[4], b[4];
#pragma unroll
      for (int i = 0; i < 4; ++i) a[i] = frag_ld(At, wm + i * 16, ks * 4 + q, l15);
#pragma unroll
      for (int j = 0; j < 4; ++j) b[j] = frag_ld(Btl, wn + j * 16, ks * 4 + q, l15);
#pragma unroll
      for (int i = 0; i < 4; ++i)
#pragma unroll
        for (int j = 0; j < 4; ++j) acc[i][j] = MFMA16(a[i], b[j], acc[i][j]);
    }
    __syncthreads();
  }
#pragma unroll
  for (int i = 0; i < 4; ++i) {
    int r0 = mt * 128 + wm + i * 16 + q * 4;
#pragma unroll
    for (int j = 0; j < 4; ++j) {
      int c = nt * 128 + wn + j * 16 + l15;
#pragma unroll
      for (int e = 0; e < 4; ++e) {
        float v = acc[i][j][e];
        if (BIAS == 1) v += bias[c];
        if (BIAS == 2) v += bias[r0 + e];
        size_t off = (size_t)(r0 + e) * ldc + c;
        if (OUTF32) ((float*)Cv)[off] = v;
        else ((uint16_t*)Cv)[off] = f2bf(v);
      }
    }
  }
}

// ---------------- pass 1: linv4[b,h,q] = 0.25 / sum_k exp(q.k/8) ------------
// grid = (S/128, H, B); 256 threads; wave = 32 q-rows x 128 k-cols
__global__ __launch_bounds__(256) void attn_lsum(const uint16_t* __restrict__ Qb,
                                                 const uint16_t* __restrict__ Kb,
                                                 float* __restrict__ linv4) {
  __shared__ char lds[32768];
  char* Qt = lds;
  char* Kt = lds + 16384;
  int tid = threadIdx.x, lane = tid & 63, wid = tid >> 6;
  int l15 = lane & 15, q = lane >> 4;
  int b = blockIdx.z, h = blockIdx.y, qt = blockIdx.x;
  const char* Qg = (const char*)(Qb + ((size_t)b * S2048 + qt * 128) * DMODEL + h * DK);
  const char* Kg = (const char*)(Kb + ((size_t)b * S2048) * DMODEL + h * DK);
  stage64(Qg, DMODEL * 2, Qt, tid, 128);
  float ps[2][4] = {};
  for (int kt = 0; kt < 16; ++kt) {
    stage64(Kg + (size_t)kt * 128 * (DMODEL * 2), DMODEL * 2, Kt, tid, 128);
    __syncthreads();
#pragma unroll
    for (int i = 0; i < 2; ++i) {
      bf16x8 a0 = frag_ld(Qt, wid * 32 + i * 16, q, l15);
      bf16x8 a1 = frag_ld(Qt, wid * 32 + i * 16, 4 + q, l15);
#pragma unroll
      for (int j = 0; j < 8; ++j) {
        f32x4 s = {0.f, 0.f, 0.f, 0.f};
        s = MFMA16(a0, frag_ld(Kt, j * 16, q, l15), s);
        s = MFMA16(a1, frag_ld(Kt, j * 16, 4 + q, l15), s);
#pragma unroll
        for (int e = 0; e < 4; ++e) ps[i][e] += __expf(s[e] * 0.125f);
      }
    }
    __syncthreads();
  }
#pragma unroll
  for (int i = 0; i < 2; ++i)
#pragma unroll
    for (int e = 0; e < 4; ++e) {
      float v = ps[i][e];
      v += __shfl_xor(v, 1); v += __shfl_xor(v, 2);
      v += __shfl_xor(v, 4); v += __shfl_xor(v, 8);
      if (l15 == 0) {
        int row = qt * 128 + wid * 32 + i * 16 + q * 4 + e;
        linv4[((size_t)(b * NH + h)) * S2048 + row] = 0.25f / v;
      }
    }
}

// ---------------- pass 2: avg_attn[b,q,k] = sum_h exp(s_h)*linv4[b,h,q] ------
// grid = (4 k-slices of 512, S/64, B); 256 threads; wave = 16 q-rows x 128 k
__global__ __launch_bounds__(256) void attn_avg(const uint16_t* __restrict__ Qb,
                                                const uint16_t* __restrict__ Kb,
                                                const float* __restrict__ linv4,
                                                float* __restrict__ attn) {
  __shared__ char lds[65536];
  char* Qt = lds;  // 4 heads x 8KB; K double-buffer at 32768 + (buf<<14)
  int tid = threadIdx.x, lane = tid & 63, wid = tid >> 6;
  int l15 = lane & 15, q = lane >> 4;
  int b = blockIdx.z, qt = blockIdx.y, kslice = blockIdx.x;
  size_t qrow0 = (size_t)b * S2048 + qt * 64;
#pragma unroll
  for (int h = 0; h < NH; ++h)
    stage64((const char*)(Qb + qrow0 * DMODEL + h * DK), DMODEL * 2, Qt + h * 8192, tid, 64);
  float li[4][4];
#pragma unroll
  for (int h = 0; h < NH; ++h)
#pragma unroll
    for (int e = 0; e < 4; ++e)
      li[h][e] = linv4[((size_t)(b * NH + h)) * S2048 + qt * 64 + wid * 16 + q * 4 + e];
  const char* Kg = (const char*)(Kb + ((size_t)b * S2048 + kslice * 512) * DMODEL);
  stage64(Kg, DMODEL * 2, lds + 32768, tid, 128);  // step 0 (kt=0,h=0)
  f32x4 Pav[8] = {};
  __syncthreads();
  for (int s = 0; s < 16; ++s) {
    int kt = s >> 2, h = s & 3;
    if (s + 1 < 16) {
      int kt2 = (s + 1) >> 2, h2 = (s + 1) & 3;
      stage64(Kg + (size_t)kt2 * 128 * (DMODEL * 2) + h2 * 128, DMODEL * 2,
              lds + 32768 + (((s + 1) & 1) << 14), tid, 128);
    }
    const char* Kc = lds + 32768 + ((s & 1) << 14);
    const char* Qh = Qt + h * 8192;
    bf16x8 a0 = frag_ld(Qh, wid * 16, q, l15);
    bf16x8 a1 = frag_ld(Qh, wid * 16, 4 + q, l15);
#pragma unroll
    for (int j = 0; j < 8; ++j) {
      f32x4 sA = {0.f, 0.f, 0.f, 0.f};
      sA = MFMA16(a0, frag_ld(Kc, j * 16, q, l15), sA);
      sA = MFMA16(a1, frag_ld(Kc, j * 16, 4 + q, l15), sA);
#pragma unroll
      for (int e = 0; e < 4; ++e) Pav[j][e] += __expf(sA[e] * 0.125f) * li[h][e];
    }
    if (h == 3) {
      size_t rowb = qrow0 + wid * 16 + q * 4;
      int colb = kslice * 512 + kt * 128 + l15;
#pragma unroll
      for (int j = 0; j < 8; ++j) {
#pragma unroll
        for (int e = 0; e < 4; ++e) {
          attn[(rowb + e) * S2048 + colb + j * 16] = Pav[j][e];
          Pav[j][e] = 0.f;
        }
      }
    }
    __syncthreads();
  }
}

// ---------------- PV: out1[b,q,d] = avg_attn[b,q,:] @ V[b,:,d] --------------
// A = avg_attn fp32 (cvt->bf16 in staging), Bt = VbT (256 x 16384 bf16)
// grid = (S/128, D/128, B)
__global__ __launch_bounds__(256) void pv_gemm(const float* __restrict__ attn,
                                               const uint16_t* __restrict__ VbT,
                                               uint16_t* __restrict__ out1) {
  __shared__ char lds[32768];
  char* At = lds;
  char* Btl = lds + 16384;
  int tid = threadIdx.x, lane = tid & 63, wid = tid >> 6;
  int l15 = lane & 15, q = lane >> 4;
  int mt = blockIdx.x, nt = blockIdx.y, b = blockIdx.z;
  int wm = (wid >> 1) * 64, wn = (wid & 1) * 64;
  f32x4 acc[4][4] = {};
  const float* Ag = attn + ((size_t)b * S2048 + mt * 128) * S2048;
  const char* Bg = (const char*)(VbT + (size_t)(nt * 128) * 16384 + (size_t)b * S2048);
  for (int kt = 0; kt < 32; ++kt) {
#pragma unroll
    for (int it = 0; it < 4; ++it) {
      int cid = it * 256 + tid;
      int m = cid >> 3, cp = cid & 7, c = cp ^ (m & 7);
      const float* src = Ag + (size_t)m * S2048 + kt * 64 + c * 8;
      float4 f0 = *(const float4*)src;
      float4 f1 = *(const float4*)(src + 4);
      union { uint16_t s[8]; uint4 u; } r;
      r.s[0] = f2bf(f0.x); r.s[1] = f2bf(f0.y); r.s[2] = f2bf(f0.z); r.s[3] = f2bf(f0.w);
      r.s[4] = f2bf(f1.x); r.s[5] = f2bf(f1.y); r.s[6] = f2bf(f1.z); r.s[7] = f2bf(f1.w);
      *(uint4*)(At + (size_t)cid * 16) = r.u;
    }
    stage64(Bg + kt * 128, 16384 * 2, Btl, tid, 128);
    __syncthreads();
#pragma unroll
    for (int ks = 0; ks < 2; ++ks) {
      bf16x8 a[4], bb[4];
#pragma unroll
      for (int i = 0; i < 4; ++i) a[i] = frag_ld(At, wm + i * 16, ks * 4 + q, l15);
#pragma unroll
      for (int j = 0; j < 4; ++j) bb[j] = frag_ld(Btl, wn + j * 16, ks * 4 + q, l15);
#pragma unroll
      for (int i = 0; i < 4; ++i)
#pragma unroll
        for (int j = 0; j < 4; ++j) acc[i][j] = MFMA16(a[i], bb[j], acc[i][j]);
    }
    __syncthreads();
  }
#pragma unroll
  for (int i = 0; i < 4; ++i) {
    size_t r0 = (size_t)b * S2048 + mt * 128 + wm + i * 16 + q * 4;
#pragma unroll
    for (int j = 0; j < 4; ++j) {
      int c = nt * 128 + wn + j * 16 + l15;
#pragma unroll
      for (int e = 0; e < 4; ++e) out1[(r0 + e) * DMODEL + c] = f2bf(acc[i][j][e]);
    }
  }
}

extern "C" void kernel_launch(void* const* d_in, const int* in_sizes, int n_in,
                              void* d_out, int out_size, void* d_ws, size_t ws_size,
                              hipStream_t stream) {
  const float* query = (const float*)d_in[0];
  const float* key_i = (const float*)d_in[1];
  const float* value = (const float*)d_in[2];
  const float* W_q = (const float*)d_in[3];
  const float* b_q = (const float*)d_in[4];
  const float* W_k = (const float*)d_in[5];
  const float* b_k = (const float*)d_in[6];
  const float* W_v = (const float*)d_in[7];
  const float* b_v = (const float*)d_in[8];
  const float* W_o = (const float*)d_in[9];
  const float* b_o = (const float*)d_in[10];

  char* ws = (char*)d_ws;
  const size_t SZX = 16384ull * 256 * 2;  // one bf16 token matrix = 8 MB
  uint16_t* Xq = (uint16_t*)(ws + 0 * SZX);
  uint16_t* Xk = (uint16_t*)(ws + 1 * SZX);
  uint16_t* Xv = (uint16_t*)(ws + 2 * SZX);
  uint16_t* Qb = (uint16_t*)(ws + 3 * SZX);
  uint16_t* Kb = (uint16_t*)(ws + 4 * SZX);
  uint16_t* VbT = (uint16_t*)(ws + 5 * SZX);   // (256 x 16384) = V^T
  uint16_t* out1b = (uint16_t*)(ws + 6 * SZX);
  uint16_t* Wqt = (uint16_t*)(ws + 7 * SZX);
  uint16_t* Wkt = (uint16_t*)(ws + 7 * SZX + 131072);
  uint16_t* Wvt = (uint16_t*)(ws + 7 * SZX + 2 * 131072);
  uint16_t* Wot = (uint16_t*)(ws + 7 * SZX + 3 * 131072);
  float* linv4 = (float*)(ws + 7 * SZX + 4 * 131072);

  float* out = (float*)d_out;
  float* attn = out + 16384ull * 256;  // avg_attn region of d_out

  cast_x<<<dim3(2048, 3), 256, 0, stream>>>(query, key_i, value, Xq, Xk, Xv);
  cast_w<<<dim3(16, 4), 256, 0, stream>>>(W_q, W_k, W_v, W_o, Wqt, Wkt, Wvt, Wot);
  // Q = Xq @ Wq + bq  (col bias)
  gemm_bt<0, 1><<<dim3(128, 2), 256, 0, stream>>>(Xq, Wqt, b_q, Qb, 256, 256);
  gemm_bt<0, 1><<<dim3(128, 2), 256, 0, stream>>>(Xk, Wkt, b_k, Kb, 256, 256);
  // VbT[d][s] = sum_k Wvt[d][k] * Xv[s][k] + bv[d]  (row bias) -> V^T directly
  gemm_bt<0, 2><<<dim3(2, 128), 256, 0, stream>>>(Wvt, Xv, b_v, VbT, 256, 16384);
  attn_lsum<<<dim3(16, 4, 8), 256, 0, stream>>>(Qb, Kb, linv4);
  attn_avg<<<dim3(4, 32, 8), 256, 0, stream>>>(Qb, Kb, linv4, attn);
  pv_gemm<<<dim3(16, 2, 8), 256, 0, stream>>>(attn, VbT, out1b);
  gemm_bt<1, 1><<<dim3(128, 2), 256, 0, stream>>>(out1b, Wot, b_o, out, 256, 256);
}